// Round 4
// baseline (192.235 us; speedup 1.0000x reference)
//
#include <hip/hip_runtime.h>
#include <hip/hip_bf16.h>

typedef __attribute__((ext_vector_type(8))) __bf16 bf16x8;
typedef __attribute__((ext_vector_type(4))) float f32x4;

#define N_NODES 50000
#define N_EDGES 800000
#define N_TILES (N_EDGES / 16)   // 50000 16-edge tiles
#define WAVES 4
#define TPW 8
#define TILES_PER_BLOCK (WAVES * TPW)   // 32 tiles -> 512 edges/block

__global__ __launch_bounds__(256, 2) void edge_mlp_kernel(
    const float* __restrict__ x_s, const float* __restrict__ x_t,
    const int* __restrict__ edge_index, const float* __restrict__ edge_attr,
    const float* __restrict__ u, const int* __restrict__ batch_e,
    const float* __restrict__ W1, const float* __restrict__ b1,
    const float* __restrict__ W2, const float* __restrict__ b2,
    float* __restrict__ out)
{
    __shared__ __align__(16) __bf16 sW1t[64][264];      // [n][k] 33792 B (staging only)
    __shared__ __align__(16) __bf16 sW2t[64][72];       // [n_out][n_in] 9216 B
    __shared__ __align__(16) __bf16 sH1[WAVES][16][76]; // pad 76: write banks {0,24,16,8}

    const int t = threadIdx.x;

    for (int idx = t; idx < 256 * 64; idx += 256) {
        int k = idx >> 6, n = idx & 63;
        sW1t[n][k] = (__bf16)W1[idx];
    }
    for (int idx = t; idx < 64 * 64; idx += 256) {
        int k = idx >> 6, n = idx & 63;
        sW2t[n][k] = (__bf16)W2[idx];   // sW2t[n_out][n_in] = W2^T
    }
    __syncthreads();

    const int wave = t >> 6;
    const int lane = t & 63;
    const int l15  = lane & 15;   // A row / B col within 16
    const int lk   = lane >> 4;   // k-group 0..3

    // ---- hoist W1 B-fragments into registers: 32 x bf16x8 = 128 VGPR ----
    bf16x8 bw1[8][4];
    #pragma unroll
    for (int kk = 0; kk < 8; ++kk)
        #pragma unroll
        for (int nf = 0; nf < 4; ++nf)
            bw1[kk][nf] = *(const bf16x8*)&sW1t[nf * 16 + l15][kk * 32 + lk * 8];

    // ---- bias registers ----
    float bv1[4];
    #pragma unroll
    for (int nf = 0; nf < 4; ++nf) bv1[nf] = b1[nf * 16 + l15];
    f32x4 bias2frag[4];          // acc2 init: element (mf, r) -> b2[mf*16+lk*4+r]
    #pragma unroll
    for (int mf = 0; mf < 4; ++mf)
        #pragma unroll
        for (int r = 0; r < 4; ++r)
            bias2frag[mf][r] = b2[mf * 16 + lk * 4 + r];

    const int tile_base = (blockIdx.x * WAVES + wave) * TPW;

    for (int i = 0; i < TPW; ++i) {
        const int tile = tile_base + i;
        if (tile >= N_TILES) break;
        const int e   = tile * 16 + l15;
        const int src = edge_index[e];
        const int tgt = edge_index[N_EDGES + e];
        const int bg  = batch_e[e];

        const float* seg0 = x_s + (long long)src * 64;
        const float* seg1 = x_t + (long long)tgt * 64;
        const float* seg2 = edge_attr + (long long)e * 64;
        const float* seg3 = u + (long long)bg * 64;

        // ---- gather + convert A-fragments ----
        bf16x8 a[8];
        #pragma unroll
        for (int c = 0; c < 8; ++c) {
            const float* s = (c < 2) ? seg0 : (c < 4) ? seg1 : (c < 6) ? seg2 : seg3;
            const float* p = s + ((c & 1) * 32 + lk * 8);
            float4 f0 = *(const float4*)p;
            float4 f1 = *(const float4*)(p + 4);
            a[c][0] = (__bf16)f0.x; a[c][1] = (__bf16)f0.y;
            a[c][2] = (__bf16)f0.z; a[c][3] = (__bf16)f0.w;
            a[c][4] = (__bf16)f1.x; a[c][5] = (__bf16)f1.y;
            a[c][6] = (__bf16)f1.z; a[c][7] = (__bf16)f1.w;
        }

        // ---- GEMM1: pure register MFMA, bias pre-folded into acc ----
        f32x4 acc[4];
        #pragma unroll
        for (int nf = 0; nf < 4; ++nf)
            acc[nf] = (f32x4){bv1[nf], bv1[nf], bv1[nf], bv1[nf]};
        #pragma unroll
        for (int kk = 0; kk < 8; ++kk)
            #pragma unroll
            for (int nf = 0; nf < 4; ++nf)
                acc[nf] = __builtin_amdgcn_mfma_f32_16x16x32_bf16(a[kk], bw1[kk][nf], acc[nf], 0, 0, 0);

        // ---- LeakyReLU(0.1) -> bf16 -> per-wave LDS tile (D: row=lk*4+r, col=l15) ----
        #pragma unroll
        for (int nf = 0; nf < 4; ++nf)
            #pragma unroll
            for (int r = 0; r < 4; ++r) {
                float v = acc[nf][r];
                v = (v >= 0.f) ? v : 0.1f * v;
                sH1[wave][lk * 4 + r][nf * 16 + l15] = (__bf16)v;
            }
        // same-wave LDS RAW: compiler inserts lgkmcnt wait

        // ---- GEMM2 transposed: O^T[64 x 16e] = W2^T · H1^T ----
        // A-frag: sW2t[mf*16+l15][kk2*32+lk*8..]; B-frag: sH1[wave][l15][kk2*32+lk*8..]
        f32x4 acc2[4];
        #pragma unroll
        for (int mf = 0; mf < 4; ++mf) acc2[mf] = bias2frag[mf];
        #pragma unroll
        for (int kk2 = 0; kk2 < 2; ++kk2) {
            bf16x8 bh = *(const bf16x8*)&sH1[wave][l15][kk2 * 32 + lk * 8];
            #pragma unroll
            for (int mf = 0; mf < 4; ++mf) {
                bf16x8 aw2 = *(const bf16x8*)&sW2t[mf * 16 + l15][kk2 * 32 + lk * 8];
                acc2[mf] = __builtin_amdgcn_mfma_f32_16x16x32_bf16(aw2, bh, acc2[mf], 0, 0, 0);
            }
        }

        // ---- store: D row = n_out (mf*16+lk*4+r), col = edge (l15) ----
        // lane holds 4 CONSECUTIVE floats of out row e: float4 stores
        float* orow = out + (long long)e * 64;
        #pragma unroll
        for (int mf = 0; mf < 4; ++mf)
            *(f32x4*)&orow[mf * 16 + lk * 4] = acc2[mf];
    }
}

extern "C" void kernel_launch(void* const* d_in, const int* in_sizes, int n_in,
                              void* d_out, int out_size, void* d_ws, size_t ws_size,
                              hipStream_t stream) {
    const float* x_s       = (const float*)d_in[0];
    const float* x_t       = (const float*)d_in[1];
    const int*   edge_index= (const int*)d_in[2];   // harness: integer -> int32
    const float* edge_attr = (const float*)d_in[3];
    const float* u         = (const float*)d_in[4];
    const int*   batch_e   = (const int*)d_in[5];
    const float* W1        = (const float*)d_in[6];
    const float* b1        = (const float*)d_in[7];
    const float* W2        = (const float*)d_in[8];
    const float* b2        = (const float*)d_in[9];
    float*       out       = (float*)d_out;

    const int nblocks = (N_TILES + TILES_PER_BLOCK - 1) / TILES_PER_BLOCK; // 1563
    edge_mlp_kernel<<<nblocks, 256, 0, stream>>>(
        x_s, x_t, edge_index, edge_attr, u, batch_e, W1, b1, W2, b2, out);
}